// Round 1
// baseline (464.646 us; speedup 1.0000x reference)
//
#include <hip/hip_runtime.h>
#include <hip/hip_bf16.h>

typedef short bf16x8 __attribute__((ext_vector_type(8)));
typedef float f32x4 __attribute__((ext_vector_type(4)));
typedef unsigned short u16;
typedef unsigned short u16x8 __attribute__((ext_vector_type(8)));

constexpr int D_IN = 2048, D_OUT = 2048, NH = 16, HD = 128, LAT = 256;
constexpr int Bb = 2, Ss = 2048, Mtot = Bb * Ss;  // 4096

__device__ __forceinline__ u16 f2bf(float f) {
  unsigned u = __float_as_uint(f);
  unsigned r = ((u >> 16) & 1u) + 0x7fffu;  // RNE
  return (u16)((u + r) >> 16);
}

// ---------- fp32 -> bf16 convert (vectorized) ----------
__global__ void k_cvt(const float* __restrict__ in, u16* __restrict__ out, int n) {
  int i = (blockIdx.x * blockDim.x + threadIdx.x) * 4;
  if (i >= n) return;
  float4 v = *reinterpret_cast<const float4*>(in + i);
  ushort4 o;
  o.x = f2bf(v.x); o.y = f2bf(v.y); o.z = f2bf(v.z); o.w = f2bf(v.w);
  *reinterpret_cast<ushort4*>(out + i) = o;
}

// ---------- transpose + convert: in [K][N] f32 -> out [N][K] bf16 ----------
__global__ void k_tcvt(const float* __restrict__ in, u16* __restrict__ out, int K, int N) {
  __shared__ float t[32][33];
  int bx = blockIdx.x * 32;  // N
  int by = blockIdx.y * 32;  // K
  int tx = threadIdx.x, ty = threadIdx.y;
#pragma unroll
  for (int j = 0; j < 32; j += 8)
    t[ty + j][tx] = in[(size_t)(by + ty + j) * N + bx + tx];
  __syncthreads();
#pragma unroll
  for (int j = 0; j < 32; j += 8)
    out[(size_t)(bx + ty + j) * K + by + tx] = f2bf(t[tx][ty + j]);
}

// ---------- GEMM: C[M,N] = A[M,K](bf16, row-major) x Bt[N,K](bf16, row-major)^T ----------
// 128x128 tile, BK=32, 4 waves (2x2), each wave 64x64 via 4x4 16x16x32 MFMA frags.
template <int OUT_MODE>  // 0: bf16 out, 1: f32 out + bias
__global__ __launch_bounds__(256) void k_gemm(const u16* __restrict__ A,
                                              const u16* __restrict__ Bt,
                                              void* __restrict__ Cp,
                                              const float* __restrict__ bias,
                                              int M, int N, int K) {
  constexpr int BK = 32, LDSS = 40;  // 40 elems = 80B stride (16B aligned, bank-balanced)
  __shared__ u16 As[128 * LDSS];
  __shared__ u16 Bs[128 * LDSS];
  const int nbx = N >> 7;
  const int bx = blockIdx.x % nbx, by = blockIdx.x / nbx;
  const int row0 = by << 7, col0 = bx << 7;
  const int tid = threadIdx.x;
  const int wave = tid >> 6, lane = tid & 63;
  const int wr = (wave >> 1) * 64, wc = (wave & 1) * 64;
  const int lr = lane & 15, lg = lane >> 4;

  f32x4 acc[4][4];
#pragma unroll
  for (int m = 0; m < 4; ++m)
#pragma unroll
    for (int n = 0; n < 4; ++n) acc[m][n] = (f32x4)0.0f;

  const int sr = tid >> 1, so = (tid & 1) * 16;
  const u16* ga = A + (size_t)(row0 + sr) * K + so;
  const u16* gb = Bt + (size_t)(col0 + sr) * K + so;
  u16* la = &As[sr * LDSS + so];
  u16* lb = &Bs[sr * LDSS + so];

  for (int k0 = 0; k0 < K; k0 += BK) {
    int4 a0 = *reinterpret_cast<const int4*>(ga + k0);
    int4 a1 = *reinterpret_cast<const int4*>(ga + k0 + 8);
    int4 b0 = *reinterpret_cast<const int4*>(gb + k0);
    int4 b1 = *reinterpret_cast<const int4*>(gb + k0 + 8);
    *reinterpret_cast<int4*>(la) = a0;
    *reinterpret_cast<int4*>(la + 8) = a1;
    *reinterpret_cast<int4*>(lb) = b0;
    *reinterpret_cast<int4*>(lb + 8) = b1;
    __syncthreads();
    bf16x8 af[4], bfr[4];
#pragma unroll
    for (int m = 0; m < 4; ++m)
      af[m] = *reinterpret_cast<const bf16x8*>(&As[(wr + m * 16 + lr) * LDSS + lg * 8]);
#pragma unroll
    for (int n = 0; n < 4; ++n)
      bfr[n] = *reinterpret_cast<const bf16x8*>(&Bs[(wc + n * 16 + lr) * LDSS + lg * 8]);
#pragma unroll
    for (int m = 0; m < 4; ++m)
#pragma unroll
      for (int n = 0; n < 4; ++n)
        acc[m][n] = __builtin_amdgcn_mfma_f32_16x16x32_bf16(af[m], bfr[n], acc[m][n], 0, 0, 0);
    __syncthreads();
  }

#pragma unroll
  for (int m = 0; m < 4; ++m) {
    const int r = row0 + wr + m * 16 + lg * 4;
#pragma unroll
    for (int n = 0; n < 4; ++n) {
      const int c = col0 + wc + n * 16 + lr;
#pragma unroll
      for (int i = 0; i < 4; ++i) {
        float v = acc[m][n][i];
        if (OUT_MODE == 0)
          ((u16*)Cp)[(size_t)(r + i) * N + c] = f2bf(v);
        else
          ((float*)Cp)[(size_t)(r + i) * N + c] = v + bias[c];
      }
    }
  }
}

// ---------- causal flash attention ----------
// grid (S/64, B*NH), 256 threads. Per block: 64 q-rows of one (b,h).
// Wave w owns q rows w*16..w*16+15. K-tiles of 64 keys, kt <= qt only.
constexpr float SM_SCALE = 0.08838834764831845f;  // 1/sqrt(128)

__global__ __launch_bounds__(256) void k_attn(const u16* __restrict__ Q,
                                              const u16* __restrict__ KV,
                                              u16* __restrict__ O) {
  constexpr int QB = 64, KB = 64;
  constexpr int LQ = 136, LV = 72, LP = 72;  // strides (elems); all rows 16B-aligned
  __shared__ u16 Qs[QB * LQ];
  __shared__ u16 Ks[KB * LQ];
  __shared__ u16 Vt[HD * LV];  // V transposed: [d][key]
  __shared__ u16 Ps[QB * LP];

  const int qt = blockIdx.x, bh = blockIdx.y;
  const int b = bh >> 4, h = bh & 15;
  const u16* Qb = Q + (size_t)b * Ss * D_OUT + h * HD;
  const u16* Kb = KV + (size_t)b * Ss * (2 * D_OUT) + h * HD;
  const u16* Vb = Kb + D_OUT;
  u16* Ob = O + (size_t)b * Ss * D_OUT + h * HD;

  const int tid = threadIdx.x, wave = tid >> 6, lane = tid & 63;
  const int lr = lane & 15, lg = lane >> 4;

  {  // stage Q tile once
    int r = tid >> 2, o = (tid & 3) * 32;
    const u16* src = Qb + (size_t)(qt * QB + r) * D_OUT + o;
    u16* dst = &Qs[r * LQ + o];
#pragma unroll
    for (int c = 0; c < 4; ++c)
      *reinterpret_cast<int4*>(dst + c * 8) = *reinterpret_cast<const int4*>(src + c * 8);
  }
  __syncthreads();
  bf16x8 qf[4];
#pragma unroll
  for (int kk = 0; kk < 4; ++kk)
    qf[kk] = *reinterpret_cast<const bf16x8*>(&Qs[(wave * 16 + lr) * LQ + kk * 32 + lg * 8]);

  f32x4 o_acc[8];
#pragma unroll
  for (int n = 0; n < 8; ++n) o_acc[n] = (f32x4)0.0f;
  float mrow[4], lrow[4];
#pragma unroll
  for (int i = 0; i < 4; ++i) { mrow[i] = -INFINITY; lrow[i] = 0.0f; }

  const int qrow_lane = qt * QB + wave * 16 + lg * 4;  // + i

  for (int kt = 0; kt <= qt; ++kt) {
    __syncthreads();  // prev iter's Ks/Vt reads done before overwrite
    {                 // stage K tile
      int r = tid >> 2, o = (tid & 3) * 32;
      const u16* src = Kb + (size_t)(kt * KB + r) * (2 * D_OUT) + o;
      u16* dst = &Ks[r * LQ + o];
#pragma unroll
      for (int c = 0; c < 4; ++c)
        *reinterpret_cast<int4*>(dst + c * 8) = *reinterpret_cast<const int4*>(src + c * 8);
    }
    {  // stage V transposed: wave handles d0=wave*32, key=lane
      int d0 = wave * 32;
      const u16* src = Vb + (size_t)(kt * KB + lane) * (2 * D_OUT) + d0;
      u16x8 v[4];
#pragma unroll
      for (int c = 0; c < 4; ++c)
        v[c] = *reinterpret_cast<const u16x8*>(src + c * 8);
#pragma unroll
      for (int c = 0; c < 4; ++c)
#pragma unroll
        for (int j = 0; j < 8; ++j)
          Vt[(d0 + c * 8 + j) * LV + lane] = v[c][j];
    }
    __syncthreads();

    // QK^T: wave's 16 q-rows x 64 keys
    f32x4 sc[4];
#pragma unroll
    for (int n = 0; n < 4; ++n) sc[n] = (f32x4)0.0f;
#pragma unroll
    for (int kk = 0; kk < 4; ++kk) {
#pragma unroll
      for (int n = 0; n < 4; ++n) {
        bf16x8 kf = *reinterpret_cast<const bf16x8*>(&Ks[(n * 16 + lr) * LQ + kk * 32 + lg * 8]);
        sc[n] = __builtin_amdgcn_mfma_f32_16x16x32_bf16(qf[kk], kf, sc[n], 0, 0, 0);
      }
    }

    // mask + scale + online softmax
    float z[4][4];
    float mt[4] = {-INFINITY, -INFINITY, -INFINITY, -INFINITY};
#pragma unroll
    for (int n = 0; n < 4; ++n) {
      int kcol = kt * KB + n * 16 + lr;
#pragma unroll
      for (int i = 0; i < 4; ++i) {
        float v = sc[n][i] * SM_SCALE;
        if (kcol > qrow_lane + i) v = -INFINITY;
        z[n][i] = v;
        mt[i] = fmaxf(mt[i], v);
      }
    }
#pragma unroll
    for (int i = 0; i < 4; ++i) {
      mt[i] = fmaxf(mt[i], __shfl_xor(mt[i], 1));
      mt[i] = fmaxf(mt[i], __shfl_xor(mt[i], 2));
      mt[i] = fmaxf(mt[i], __shfl_xor(mt[i], 4));
      mt[i] = fmaxf(mt[i], __shfl_xor(mt[i], 8));
    }
    float r_[4], psum[4];
#pragma unroll
    for (int i = 0; i < 4; ++i) {
      float mn = fmaxf(mrow[i], mt[i]);
      r_[i] = expf(mrow[i] - mn);
      mrow[i] = mn;
      psum[i] = 0.0f;
    }
#pragma unroll
    for (int n = 0; n < 4; ++n)
#pragma unroll
      for (int i = 0; i < 4; ++i) {
        float p = expf(z[n][i] - mrow[i]);  // exp(-inf)=0 handles mask
        z[n][i] = p;
        psum[i] += p;
      }
#pragma unroll
    for (int i = 0; i < 4; ++i) {
      psum[i] += __shfl_xor(psum[i], 1);
      psum[i] += __shfl_xor(psum[i], 2);
      psum[i] += __shfl_xor(psum[i], 4);
      psum[i] += __shfl_xor(psum[i], 8);
      lrow[i] = lrow[i] * r_[i] + psum[i];
    }
#pragma unroll
    for (int n = 0; n < 8; ++n) {
      f32x4 t = o_acc[n];
      t[0] *= r_[0]; t[1] *= r_[1]; t[2] *= r_[2]; t[3] *= r_[3];
      o_acc[n] = t;
    }
    // write P tile (this wave's 16 rows) to LDS as bf16
#pragma unroll
    for (int n = 0; n < 4; ++n)
#pragma unroll
      for (int i = 0; i < 4; ++i)
        Ps[(wave * 16 + lg * 4 + i) * LP + n * 16 + lr] = f2bf(z[n][i]);
    __syncthreads();

    // PV: o_acc[16 x 128] += P[16 x 64] @ V[64 x 128]
#pragma unroll
    for (int kk = 0; kk < 2; ++kk) {
      bf16x8 pa = *reinterpret_cast<const bf16x8*>(&Ps[(wave * 16 + lr) * LP + kk * 32 + lg * 8]);
#pragma unroll
      for (int n = 0; n < 8; ++n) {
        bf16x8 bv = *reinterpret_cast<const bf16x8*>(&Vt[(n * 16 + lr) * LV + kk * 32 + lg * 8]);
        o_acc[n] = __builtin_amdgcn_mfma_f32_16x16x32_bf16(pa, bv, o_acc[n], 0, 0, 0);
      }
    }
  }

  // epilogue: normalize + store ctx (bf16)
#pragma unroll
  for (int n = 0; n < 8; ++n) {
#pragma unroll
    for (int i = 0; i < 4; ++i) {
      float v = o_acc[n][i] / lrow[i];
      Ob[(size_t)(qt * QB + wave * 16 + lg * 4 + i) * D_OUT + n * 16 + lr] = f2bf(v);
    }
  }
}

extern "C" void kernel_launch(void* const* d_in, const int* in_sizes, int n_in,
                              void* d_out, int out_size, void* d_ws, size_t ws_size,
                              hipStream_t stream) {
  const float* x    = (const float*)d_in[0];
  const float* Wq   = (const float*)d_in[1];
  const float* Wdkv = (const float*)d_in[2];
  const float* Wukv = (const float*)d_in[3];
  const float* Wout = (const float*)d_in[4];
  const float* bout = (const float*)d_in[5];
  float* out = (float*)d_out;

  char* ws = (char*)d_ws;
  size_t off = 0;
  auto alloc = [&](size_t bytes) -> void* {
    void* p = ws + off;
    off += (bytes + 255) & ~(size_t)255;
    return p;
  };
  u16* xb    = (u16*)alloc((size_t)Mtot * D_IN * 2);       // x bf16
  u16* wqT   = (u16*)alloc((size_t)D_OUT * D_IN * 2);      // Wq^T
  u16* wdkvT = (u16*)alloc((size_t)LAT * D_IN * 2);        // Wdkv^T
  u16* wukvT = (u16*)alloc((size_t)2 * D_OUT * LAT * 2);   // Wukv^T
  u16* woutT = (u16*)alloc((size_t)D_IN * D_OUT * 2);      // Wout^T
  u16* q     = (u16*)alloc((size_t)Mtot * D_OUT * 2);      // Q
  u16* lat   = (u16*)alloc((size_t)Mtot * LAT * 2);        // latent
  u16* kv    = (u16*)alloc((size_t)Mtot * 2 * D_OUT * 2);  // K|V
  u16* ctx   = (u16*)alloc((size_t)Mtot * D_OUT * 2);      // attention out

  {
    int n = Mtot * D_IN;
    k_cvt<<<n / 4 / 256, 256, 0, stream>>>(x, xb, n);
  }
  k_tcvt<<<dim3(D_OUT / 32, D_IN / 32), dim3(32, 8), 0, stream>>>(Wq, wqT, D_IN, D_OUT);
  k_tcvt<<<dim3(LAT / 32, D_IN / 32), dim3(32, 8), 0, stream>>>(Wdkv, wdkvT, D_IN, LAT);
  k_tcvt<<<dim3(2 * D_OUT / 32, LAT / 32), dim3(32, 8), 0, stream>>>(Wukv, wukvT, LAT, 2 * D_OUT);
  k_tcvt<<<dim3(D_IN / 32, D_OUT / 32), dim3(32, 8), 0, stream>>>(Wout, woutT, D_OUT, D_IN);

  // q = x @ Wq
  k_gemm<0><<<(Mtot / 128) * (D_OUT / 128), 256, 0, stream>>>(xb, wqT, q, nullptr, Mtot, D_OUT, D_IN);
  // latent = x @ Wdkv
  k_gemm<0><<<(Mtot / 128) * (LAT / 128), 256, 0, stream>>>(xb, wdkvT, lat, nullptr, Mtot, LAT, D_IN);
  // kv = latent @ Wukv
  k_gemm<0><<<(Mtot / 128) * (2 * D_OUT / 128), 256, 0, stream>>>(lat, wukvT, kv, nullptr, Mtot, 2 * D_OUT, LAT);
  // attention
  k_attn<<<dim3(Ss / 64, Bb * NH), 256, 0, stream>>>(q, kv, ctx);
  // out = ctx @ Wout + b_out
  k_gemm<1><<<(Mtot / 128) * (D_IN / 128), 256, 0, stream>>>(ctx, woutT, out, bout, Mtot, D_IN, D_OUT);
}

// Round 2
// 430.593 us; speedup vs baseline: 1.0791x; 1.0791x over previous
//
#include <hip/hip_runtime.h>
#include <hip/hip_bf16.h>

typedef short bf16x8 __attribute__((ext_vector_type(8)));
typedef float f32x4 __attribute__((ext_vector_type(4)));
typedef unsigned short u16;
typedef unsigned short u16x8 __attribute__((ext_vector_type(8)));

constexpr int D_IN = 2048, D_OUT = 2048, NH = 16, HD = 128, LAT = 256;
constexpr int Bb = 2, Ss = 2048, Mtot = Bb * Ss;  // 4096

// 1/sqrt(128) * log2(e): fold softmax scale + exp2 conversion into Q once
constexpr float QSCALE = 0.08838834764831845f * 1.4426950408889634f;
constexpr float NEG_BIG = -3.0e38f;

__device__ __forceinline__ u16 f2bf(float f) {
  unsigned u = __float_as_uint(f);
  unsigned r = ((u >> 16) & 1u) + 0x7fffu;  // RNE
  return (u16)((u + r) >> 16);
}

__device__ __forceinline__ float fexp2(float x) {
#if __has_builtin(__builtin_amdgcn_exp2f)
  return __builtin_amdgcn_exp2f(x);
#else
  return exp2f(x);
#endif
}

__device__ __forceinline__ void gload_lds16(const u16* g, u16* l) {
  __builtin_amdgcn_global_load_lds((const __attribute__((address_space(1))) void*)g,
                                   (__attribute__((address_space(3))) void*)l, 16, 0, 0);
}

// ---------- fp32 -> bf16 convert (vectorized) ----------
__global__ void k_cvt(const float* __restrict__ in, u16* __restrict__ out, int n) {
  int i = (blockIdx.x * blockDim.x + threadIdx.x) * 4;
  if (i >= n) return;
  float4 v = *reinterpret_cast<const float4*>(in + i);
  ushort4 o;
  o.x = f2bf(v.x); o.y = f2bf(v.y); o.z = f2bf(v.z); o.w = f2bf(v.w);
  *reinterpret_cast<ushort4*>(out + i) = o;
}

// ---------- transpose + convert: in [K][N] f32 -> out [N][K] bf16 ----------
__global__ void k_tcvt(const float* __restrict__ in, u16* __restrict__ out, int K, int N) {
  __shared__ float t[32][33];
  int bx = blockIdx.x * 32;  // N
  int by = blockIdx.y * 32;  // K
  int tx = threadIdx.x, ty = threadIdx.y;
#pragma unroll
  for (int j = 0; j < 32; j += 8)
    t[ty + j][tx] = in[(size_t)(by + ty + j) * N + bx + tx];
  __syncthreads();
#pragma unroll
  for (int j = 0; j < 32; j += 8)
    out[(size_t)(bx + ty + j) * K + by + tx] = f2bf(t[tx][ty + j]);
}

// ---------- GEMM: C[M,N] = A[M,K](bf16 rm) x Bt[N,K](bf16 rm)^T ----------
// 128x128 tile, BK=32, 4 waves (2x2). global_load_lds width-16 staging,
// linear [128][32] LDS (dest must be wave-uniform base + lane*16 -> row=lane>>2,
// col=(lane&3)*8 matches exactly).
template <int OUT_MODE>  // 0: bf16, 1: f32 + bias, 2: bf16 * scale
__global__ __launch_bounds__(256) void k_gemm(const u16* __restrict__ A,
                                              const u16* __restrict__ Bt,
                                              void* __restrict__ Cp,
                                              const float* __restrict__ bias,
                                              float scale, int M, int N, int K) {
  constexpr int BK = 32;
  __shared__ u16 As[128 * BK];
  __shared__ u16 Bs[128 * BK];
  const int nbx = N >> 7;
  const int bx = blockIdx.x % nbx, by = blockIdx.x / nbx;
  const int row0 = by << 7, col0 = bx << 7;
  const int tid = threadIdx.x;
  const int wave = tid >> 6, lane = tid & 63;
  const int wr = (wave >> 1) * 64, wc = (wave & 1) * 64;
  const int lr = lane & 15, lg = lane >> 4;

  f32x4 acc[4][4];
#pragma unroll
  for (int m = 0; m < 4; ++m)
#pragma unroll
    for (int n = 0; n < 4; ++n) acc[m][n] = (f32x4)0.0f;

  const int crow = lane >> 2, ccol = (lane & 3) * 8;
  const u16* gA0 = A + (size_t)(row0 + wave * 32 + crow) * K + ccol;
  const u16* gA1 = gA0 + (size_t)16 * K;
  const u16* gB0 = Bt + (size_t)(col0 + wave * 32 + crow) * K + ccol;
  const u16* gB1 = gB0 + (size_t)16 * K;
  u16* lA0 = &As[(wave * 32) * BK];
  u16* lA1 = &As[(wave * 32 + 16) * BK];
  u16* lB0 = &Bs[(wave * 32) * BK];
  u16* lB1 = &Bs[(wave * 32 + 16) * BK];

  for (int k0 = 0; k0 < K; k0 += BK) {
    gload_lds16(gA0 + k0, lA0);
    gload_lds16(gA1 + k0, lA1);
    gload_lds16(gB0 + k0, lB0);
    gload_lds16(gB1 + k0, lB1);
    __syncthreads();
    bf16x8 af[4], bfr[4];
#pragma unroll
    for (int m = 0; m < 4; ++m)
      af[m] = *reinterpret_cast<const bf16x8*>(&As[(wr + m * 16 + lr) * BK + lg * 8]);
#pragma unroll
    for (int n = 0; n < 4; ++n)
      bfr[n] = *reinterpret_cast<const bf16x8*>(&Bs[(wc + n * 16 + lr) * BK + lg * 8]);
#pragma unroll
    for (int m = 0; m < 4; ++m)
#pragma unroll
      for (int n = 0; n < 4; ++n)
        acc[m][n] = __builtin_amdgcn_mfma_f32_16x16x32_bf16(af[m], bfr[n], acc[m][n], 0, 0, 0);
    __syncthreads();
  }

#pragma unroll
  for (int m = 0; m < 4; ++m) {
    const int r = row0 + wr + m * 16 + lg * 4;
#pragma unroll
    for (int n = 0; n < 4; ++n) {
      const int c = col0 + wc + n * 16 + lr;
#pragma unroll
      for (int i = 0; i < 4; ++i) {
        float v = acc[m][n][i];
        if (OUT_MODE == 0)
          ((u16*)Cp)[(size_t)(r + i) * N + c] = f2bf(v);
        else if (OUT_MODE == 1)
          ((float*)Cp)[(size_t)(r + i) * N + c] = v + bias[c];
        else
          ((u16*)Cp)[(size_t)(r + i) * N + c] = f2bf(v * scale);
      }
    }
  }
}

// ---------- causal flash attention ----------
// grid (S/64, B*NH), 256 threads / 4 waves; wave w owns q rows w*16..w*16+15.
// Q pre-scaled by 1/sqrt(d)*log2e in projection -> softmax in exp2 domain.
// T14: K/V staged to regs one tile ahead; 2 barriers/tile; T13 defer-rescale.
__global__ __launch_bounds__(256) void k_attn(const u16* __restrict__ Q,
                                              const u16* __restrict__ KV,
                                              u16* __restrict__ O) {
  constexpr int KB = 64;
  constexpr int LK = 136, LV = 72, LP = 80;
  __shared__ u16 Ks[KB * LK];
  __shared__ u16 Vt[HD * LV];  // V transposed: [d][key]
  __shared__ u16 Ps[64 * LP];

  const int qt = gridDim.x - 1 - blockIdx.x;  // big blocks first
  const int bh = blockIdx.y;
  const int b = bh >> 4, h = bh & 15;
  const u16* Qb = Q + (size_t)b * Ss * D_OUT + h * HD;
  const u16* Kb = KV + (size_t)b * Ss * (2 * D_OUT) + h * HD;
  const u16* Vb = Kb + D_OUT;
  u16* Ob = O + (size_t)b * Ss * D_OUT + h * HD;

  const int tid = threadIdx.x, wave = tid >> 6, lane = tid & 63;
  const int lr = lane & 15, lg = lane >> 4;

  // Q fragments: global -> reg (pre-scaled bf16)
  bf16x8 qf[4];
  {
    const u16* qsrc = Qb + (size_t)(qt * KB + wave * 16 + lr) * D_OUT + lg * 8;
#pragma unroll
    for (int kk = 0; kk < 4; ++kk)
      qf[kk] = *reinterpret_cast<const bf16x8*>(qsrc + kk * 32);
  }

  f32x4 o_acc[8];
#pragma unroll
  for (int n = 0; n < 8; ++n) o_acc[n] = (f32x4)0.0f;
  float mrow[4], lrow[4];
#pragma unroll
  for (int i = 0; i < 4; ++i) { mrow[i] = NEG_BIG; lrow[i] = 0.0f; }

  const int qrow = qt * KB + wave * 16 + lg * 4;  // + i
  const size_t kvstep = (size_t)KB * 2 * D_OUT;

  // staging addresses
  const int sr = tid >> 2, scl = (tid & 3) * 32;
  const u16* ksrc = Kb + (size_t)sr * (2 * D_OUT) + scl;
  const u16* vsrc = Vb + (size_t)lane * (2 * D_OUT) + wave * 32;

  int4 kreg[4];
  u16x8 vreg[4];
#pragma unroll
  for (int c = 0; c < 4; ++c) {
    kreg[c] = *reinterpret_cast<const int4*>(ksrc + c * 8);
    vreg[c] = *reinterpret_cast<const u16x8*>(vsrc + c * 8);
  }

  for (int kt = 0; kt <= qt; ++kt) {
    // write staged regs to LDS
    {
      u16* kdst = &Ks[sr * LK + scl];
#pragma unroll
      for (int c = 0; c < 4; ++c)
        *reinterpret_cast<int4*>(kdst + c * 8) = kreg[c];
#pragma unroll
      for (int c = 0; c < 4; ++c)
#pragma unroll
        for (int j = 0; j < 8; ++j)
          Vt[(wave * 32 + c * 8 + j) * LV + lane] = vreg[c][j];
    }
    __syncthreads();

    // prefetch next tile into regs (latency hidden under QK+softmax+PV)
    if (kt < qt) {
      const u16* kn = ksrc + (size_t)(kt + 1) * kvstep;
      const u16* vn = vsrc + (size_t)(kt + 1) * kvstep;
#pragma unroll
      for (int c = 0; c < 4; ++c) {
        kreg[c] = *reinterpret_cast<const int4*>(kn + c * 8);
        vreg[c] = *reinterpret_cast<const u16x8*>(vn + c * 8);
      }
    }

    // QK^T: wave's 16 q-rows x 64 keys (scores already in log2 domain)
    f32x4 sc[4];
#pragma unroll
    for (int n = 0; n < 4; ++n) sc[n] = (f32x4)0.0f;
#pragma unroll
    for (int kk = 0; kk < 4; ++kk) {
#pragma unroll
      for (int n = 0; n < 4; ++n) {
        bf16x8 kf = *reinterpret_cast<const bf16x8*>(&Ks[(n * 16 + lr) * LK + kk * 32 + lg * 8]);
        sc[n] = __builtin_amdgcn_mfma_f32_16x16x32_bf16(qf[kk], kf, sc[n], 0, 0, 0);
      }
    }

    // online softmax (log2 domain)
    float z[4][4];
    float mt[4] = {NEG_BIG, NEG_BIG, NEG_BIG, NEG_BIG};
    if (kt == qt) {  // only the diagonal tile needs masking
#pragma unroll
      for (int n = 0; n < 4; ++n) {
        int kcol = kt * KB + n * 16 + lr;
#pragma unroll
        for (int i = 0; i < 4; ++i) {
          float v = (kcol > qrow + i) ? NEG_BIG : sc[n][i];
          z[n][i] = v;
          mt[i] = fmaxf(mt[i], v);
        }
      }
    } else {
#pragma unroll
      for (int n = 0; n < 4; ++n)
#pragma unroll
        for (int i = 0; i < 4; ++i) {
          z[n][i] = sc[n][i];
          mt[i] = fmaxf(mt[i], sc[n][i]);
        }
    }
#pragma unroll
    for (int i = 0; i < 4; ++i) {
      mt[i] = fmaxf(mt[i], __shfl_xor(mt[i], 1));
      mt[i] = fmaxf(mt[i], __shfl_xor(mt[i], 2));
      mt[i] = fmaxf(mt[i], __shfl_xor(mt[i], 4));
      mt[i] = fmaxf(mt[i], __shfl_xor(mt[i], 8));
    }
    // T13 defer-rescale: skip when max grew by <= 8 (P bounded by 2^8)
    float r_[4];
    int allskip = 1;
#pragma unroll
    for (int i = 0; i < 4; ++i) {
      if (mt[i] <= mrow[i] + 8.0f) {
        r_[i] = 1.0f;
      } else {
        r_[i] = fexp2(mrow[i] - mt[i]);
        mrow[i] = mt[i];
        allskip = 0;
      }
    }
    if (!__all(allskip)) {
#pragma unroll
      for (int n = 0; n < 8; ++n) {
        f32x4 t = o_acc[n];
        t[0] *= r_[0]; t[1] *= r_[1]; t[2] *= r_[2]; t[3] *= r_[3];
        o_acc[n] = t;
      }
    }
    float psum[4] = {0.0f, 0.0f, 0.0f, 0.0f};
#pragma unroll
    for (int n = 0; n < 4; ++n)
#pragma unroll
      for (int i = 0; i < 4; ++i) {
        float p = fexp2(z[n][i] - mrow[i]);
        z[n][i] = p;
        psum[i] += p;
      }
#pragma unroll
    for (int i = 0; i < 4; ++i) {
      psum[i] += __shfl_xor(psum[i], 1);
      psum[i] += __shfl_xor(psum[i], 2);
      psum[i] += __shfl_xor(psum[i], 4);
      psum[i] += __shfl_xor(psum[i], 8);
      lrow[i] = lrow[i] * r_[i] + psum[i];
    }
    // P tile -> LDS (own wave's rows only; no cross-wave barrier needed)
#pragma unroll
    for (int n = 0; n < 4; ++n)
#pragma unroll
      for (int i = 0; i < 4; ++i)
        Ps[(wave * 16 + lg * 4 + i) * LP + n * 16 + lr] = f2bf(z[n][i]);

    // PV: o_acc[16 x 128] += P[16 x 64] @ V[64 x 128]
#pragma unroll
    for (int kk = 0; kk < 2; ++kk) {
      bf16x8 pa = *reinterpret_cast<const bf16x8*>(&Ps[(wave * 16 + lr) * LP + kk * 32 + lg * 8]);
#pragma unroll
      for (int n = 0; n < 8; ++n) {
        bf16x8 bv = *reinterpret_cast<const bf16x8*>(&Vt[(n * 16 + lr) * LV + kk * 32 + lg * 8]);
        o_acc[n] = __builtin_amdgcn_mfma_f32_16x16x32_bf16(pa, bv, o_acc[n], 0, 0, 0);
      }
    }
    __syncthreads();  // all reads of Ks/Vt done before next tile's writes
  }

  // epilogue: normalize + store ctx (bf16)
#pragma unroll
  for (int i = 0; i < 4; ++i) lrow[i] = 1.0f / lrow[i];
#pragma unroll
  for (int n = 0; n < 8; ++n) {
#pragma unroll
    for (int i = 0; i < 4; ++i) {
      float v = o_acc[n][i] * lrow[i];
      Ob[(size_t)(qt * KB + wave * 16 + lg * 4 + i) * D_OUT + n * 16 + lr] = f2bf(v);
    }
  }
}

extern "C" void kernel_launch(void* const* d_in, const int* in_sizes, int n_in,
                              void* d_out, int out_size, void* d_ws, size_t ws_size,
                              hipStream_t stream) {
  const float* x    = (const float*)d_in[0];
  const float* Wq   = (const float*)d_in[1];
  const float* Wdkv = (const float*)d_in[2];
  const float* Wukv = (const float*)d_in[3];
  const float* Wout = (const float*)d_in[4];
  const float* bout = (const float*)d_in[5];
  float* out = (float*)d_out;

  char* ws = (char*)d_ws;
  size_t off = 0;
  auto alloc = [&](size_t bytes) -> void* {
    void* p = ws + off;
    off += (bytes + 255) & ~(size_t)255;
    return p;
  };
  u16* xb    = (u16*)alloc((size_t)Mtot * D_IN * 2);
  u16* wqT   = (u16*)alloc((size_t)D_OUT * D_IN * 2);
  u16* wdkvT = (u16*)alloc((size_t)LAT * D_IN * 2);
  u16* wukvT = (u16*)alloc((size_t)2 * D_OUT * LAT * 2);
  u16* woutT = (u16*)alloc((size_t)D_IN * D_OUT * 2);
  u16* q     = (u16*)alloc((size_t)Mtot * D_OUT * 2);
  u16* lat   = (u16*)alloc((size_t)Mtot * LAT * 2);
  u16* kv    = (u16*)alloc((size_t)Mtot * 2 * D_OUT * 2);
  u16* ctx   = (u16*)alloc((size_t)Mtot * D_OUT * 2);

  {
    int n = Mtot * D_IN;
    k_cvt<<<n / 4 / 256, 256, 0, stream>>>(x, xb, n);
  }
  k_tcvt<<<dim3(D_OUT / 32, D_IN / 32), dim3(32, 8), 0, stream>>>(Wq, wqT, D_IN, D_OUT);
  k_tcvt<<<dim3(LAT / 32, D_IN / 32), dim3(32, 8), 0, stream>>>(Wdkv, wdkvT, D_IN, LAT);
  k_tcvt<<<dim3(2 * D_OUT / 32, LAT / 32), dim3(32, 8), 0, stream>>>(Wukv, wukvT, LAT, 2 * D_OUT);
  k_tcvt<<<dim3(D_IN / 32, D_OUT / 32), dim3(32, 8), 0, stream>>>(Wout, woutT, D_OUT, D_IN);

  // q = (x @ Wq) * (1/sqrt(d) * log2e)   [scale folded for log2-domain softmax]
  k_gemm<2><<<(Mtot / 128) * (D_OUT / 128), 256, 0, stream>>>(xb, wqT, q, nullptr, QSCALE, Mtot, D_OUT, D_IN);
  // latent = x @ Wdkv
  k_gemm<0><<<(Mtot / 128) * (LAT / 128), 256, 0, stream>>>(xb, wdkvT, lat, nullptr, 1.0f, Mtot, LAT, D_IN);
  // kv = latent @ Wukv
  k_gemm<0><<<(Mtot / 128) * (2 * D_OUT / 128), 256, 0, stream>>>(lat, wukvT, kv, nullptr, 1.0f, Mtot, 2 * D_OUT, LAT);
  // attention
  k_attn<<<dim3(Ss / 64, Bb * NH), 256, 0, stream>>>(q, kv, ctx);
  // out = ctx @ Wout + b_out
  k_gemm<1><<<(Mtot / 128) * (D_IN / 128), 256, 0, stream>>>(ctx, woutT, out, bout, 1.0f, Mtot, D_IN, D_OUT);
}

// Round 3
// 309.870 us; speedup vs baseline: 1.4995x; 1.3896x over previous
//
#include <hip/hip_runtime.h>
#include <hip/hip_bf16.h>

typedef short bf16x8 __attribute__((ext_vector_type(8)));
typedef float f32x4 __attribute__((ext_vector_type(4)));
typedef float f32x16 __attribute__((ext_vector_type(16)));
typedef unsigned int u32x4 __attribute__((ext_vector_type(4)));
typedef unsigned short u16;
typedef unsigned short u16x4 __attribute__((ext_vector_type(4)));
typedef unsigned short u16x8 __attribute__((ext_vector_type(8)));

constexpr int D_IN = 2048, D_OUT = 2048, NH = 16, HD = 128, LAT = 256;
constexpr int Bb = 2, Ss = 2048, Mtot = Bb * Ss;  // 4096

// 1/sqrt(128) * log2(e): fold softmax scale + exp2 conversion into Q once
constexpr float QSCALE = 0.08838834764831845f * 1.4426950408889634f;
constexpr float NEG_BIG = -3.0e38f;

__device__ __forceinline__ u16 f2bf(float f) {
  unsigned u = __float_as_uint(f);
  unsigned r = ((u >> 16) & 1u) + 0x7fffu;  // RNE
  return (u16)((u + r) >> 16);
}

__device__ __forceinline__ float fexp2(float x) {
#if __has_builtin(__builtin_amdgcn_exp2f)
  return __builtin_amdgcn_exp2f(x);
#else
  return exp2f(x);
#endif
}

__device__ __forceinline__ unsigned cvtpk(float lo, float hi) {
  unsigned r;
  asm("v_cvt_pk_bf16_f32 %0, %1, %2" : "=v"(r) : "v"(lo), "v"(hi));
  return r;
}

__device__ __forceinline__ void swap32(unsigned& a, unsigned& b) {
  asm volatile("v_permlane32_swap_b32 %0, %1" : "+v"(a), "+v"(b));
}

__device__ __forceinline__ void gload_lds16(const u16* g, u16* l) {
  __builtin_amdgcn_global_load_lds((const __attribute__((address_space(1))) void*)g,
                                   (__attribute__((address_space(3))) void*)l, 16, 0, 0);
}

// ---------- fp32 -> bf16 convert (vectorized) ----------
__global__ void k_cvt(const float* __restrict__ in, u16* __restrict__ out, int n) {
  int i = (blockIdx.x * blockDim.x + threadIdx.x) * 4;
  if (i >= n) return;
  float4 v = *reinterpret_cast<const float4*>(in + i);
  ushort4 o;
  o.x = f2bf(v.x); o.y = f2bf(v.y); o.z = f2bf(v.z); o.w = f2bf(v.w);
  *reinterpret_cast<ushort4*>(out + i) = o;
}

// ---------- transpose + convert: in [K][N] f32 -> out [N][K] bf16 ----------
__global__ void k_tcvt(const float* __restrict__ in, u16* __restrict__ out, int K, int N) {
  __shared__ float t[32][33];
  int bx = blockIdx.x * 32;  // N
  int by = blockIdx.y * 32;  // K
  int tx = threadIdx.x, ty = threadIdx.y;
#pragma unroll
  for (int j = 0; j < 32; j += 8)
    t[ty + j][tx] = in[(size_t)(by + ty + j) * N + bx + tx];
  __syncthreads();
#pragma unroll
  for (int j = 0; j < 32; j += 8)
    out[(size_t)(bx + ty + j) * K + by + tx] = f2bf(t[tx][ty + j]);
}

// ---------- GEMM: C[M,N] = A[M,K](bf16 rm) x Bt[N,K](bf16 rm)^T ----------
template <int OUT_MODE>  // 0: bf16, 1: f32 + bias, 2: bf16 * scale
__global__ __launch_bounds__(256) void k_gemm(const u16* __restrict__ A,
                                              const u16* __restrict__ Bt,
                                              void* __restrict__ Cp,
                                              const float* __restrict__ bias,
                                              float scale, int M, int N, int K) {
  constexpr int BK = 32;
  __shared__ u16 As[128 * BK];
  __shared__ u16 Bs[128 * BK];
  const int nbx = N >> 7;
  const int bx = blockIdx.x % nbx, by = blockIdx.x / nbx;
  const int row0 = by << 7, col0 = bx << 7;
  const int tid = threadIdx.x;
  const int wave = tid >> 6, lane = tid & 63;
  const int wr = (wave >> 1) * 64, wc = (wave & 1) * 64;
  const int lr = lane & 15, lg = lane >> 4;

  f32x4 acc[4][4];
#pragma unroll
  for (int m = 0; m < 4; ++m)
#pragma unroll
    for (int n = 0; n < 4; ++n) acc[m][n] = (f32x4)0.0f;

  const int crow = lane >> 2, ccol = (lane & 3) * 8;
  const u16* gA0 = A + (size_t)(row0 + wave * 32 + crow) * K + ccol;
  const u16* gA1 = gA0 + (size_t)16 * K;
  const u16* gB0 = Bt + (size_t)(col0 + wave * 32 + crow) * K + ccol;
  const u16* gB1 = gB0 + (size_t)16 * K;
  u16* lA0 = &As[(wave * 32) * BK];
  u16* lA1 = &As[(wave * 32 + 16) * BK];
  u16* lB0 = &Bs[(wave * 32) * BK];
  u16* lB1 = &Bs[(wave * 32 + 16) * BK];

  for (int k0 = 0; k0 < K; k0 += BK) {
    gload_lds16(gA0 + k0, lA0);
    gload_lds16(gA1 + k0, lA1);
    gload_lds16(gB0 + k0, lB0);
    gload_lds16(gB1 + k0, lB1);
    __syncthreads();
    bf16x8 af[4], bfr[4];
#pragma unroll
    for (int m = 0; m < 4; ++m)
      af[m] = *reinterpret_cast<const bf16x8*>(&As[(wr + m * 16 + lr) * BK + lg * 8]);
#pragma unroll
    for (int n = 0; n < 4; ++n)
      bfr[n] = *reinterpret_cast<const bf16x8*>(&Bs[(wc + n * 16 + lr) * BK + lg * 8]);
#pragma unroll
    for (int m = 0; m < 4; ++m)
#pragma unroll
      for (int n = 0; n < 4; ++n)
        acc[m][n] = __builtin_amdgcn_mfma_f32_16x16x32_bf16(af[m], bfr[n], acc[m][n], 0, 0, 0);
    __syncthreads();
  }

#pragma unroll
  for (int m = 0; m < 4; ++m) {
    const int r = row0 + wr + m * 16 + lg * 4;
#pragma unroll
    for (int n = 0; n < 4; ++n) {
      const int c = col0 + wc + n * 16 + lr;
#pragma unroll
      for (int i = 0; i < 4; ++i) {
        float v = acc[m][n][i];
        if (OUT_MODE == 0)
          ((u16*)Cp)[(size_t)(r + i) * N + c] = f2bf(v);
        else if (OUT_MODE == 1)
          ((float*)Cp)[(size_t)(r + i) * N + c] = v + bias[c];
        else
          ((u16*)Cp)[(size_t)(r + i) * N + c] = f2bf(v * scale);
      }
    }
  }
}

// ---------- causal flash attention, m214-style 32x32 swapped-QK ----------
// 512 blocks, 4 waves; wave owns 32 q-rows (QBLK=32), block 128 rows. KVBLK=64.
// Swapped QK^T: S^T = mfma(A=K, B=Q) -> lane holds P-row for q=lane&31.
// K/Vt in XOR-swizzled LDS; P->bf16 A-frags via cvt_pk + permlane32_swap.
__global__ __launch_bounds__(256) void k_attn(const u16* __restrict__ Q,
                                              const u16* __restrict__ KV,
                                              u16* __restrict__ O) {
  __shared__ __align__(16) u16 Ks[64 * 128];  // [key][d], elem ^= (key&7)<<3
  __shared__ __align__(16) u16 Vt[128 * 64];  // [d][key], elem ^= (d&7)<<3
  const int id = blockIdx.x;
  const int bh = id & 31, j = id >> 5;
  const int qb = (j & 1) ? (j >> 1) : (15 - (j >> 1));  // alternate big/small
  const int b = bh >> 4, h = bh & 15;
  const u16* Qb = Q + (size_t)b * Ss * D_OUT + h * HD;
  const u16* Kb = KV + (size_t)b * Ss * (2 * D_OUT) + h * HD;
  const u16* Vb = Kb + D_OUT;
  u16* Ob = O + (size_t)b * Ss * D_OUT + h * HD;

  const int tid = threadIdx.x, wave = tid >> 6, lane = tid & 63;
  const int lo = lane & 31, hi = lane >> 5;
  const int q0w = qb * 128 + wave * 32;  // wave's first q-row

  // Q fragments (B-operand): col=q=lane&31, k=d=(lane>>5)*8+j within 16-d step
  bf16x8 qf[8];
  {
    const u16* qsrc = Qb + (size_t)(q0w + lo) * D_OUT + hi * 8;
#pragma unroll
    for (int ds = 0; ds < 8; ++ds)
      qf[ds] = *reinterpret_cast<const bf16x8*>(qsrc + ds * 16);
  }

  f32x16 ctx[4];
#pragma unroll
  for (int dt = 0; dt < 4; ++dt) ctx[dt] = (f32x16)0.0f;
  float mrow = NEG_BIG, lrow = 0.0f;

  // staging roles
  const int sr = tid >> 2, sc = tid & 3;        // K: row sr, 16B-chunk sc + 4c
  const int vk = (tid & 15) * 4, vd = (tid >> 4) * 8;  // V: 4 keys, 8 d's
  const u16* kg = Kb + (size_t)sr * (2 * D_OUT) + sc * 8;
  const u16* vg = Vb + (size_t)vk * (2 * D_OUT) + vd;
  const size_t kvstep = (size_t)64 * 2 * D_OUT;

  int4 kreg[4];
  u16x8 vreg[4];
#pragma unroll
  for (int c = 0; c < 4; ++c) {
    kreg[c] = *reinterpret_cast<const int4*>(kg + c * 32);
    vreg[c] = *reinterpret_cast<const u16x8*>(vg + (size_t)c * (2 * D_OUT));
  }

  const int KT = 2 * qb + 2;
  for (int kt = 0; kt < KT; ++kt) {
    // staged regs -> swizzled LDS
#pragma unroll
    for (int c = 0; c < 4; ++c)
      *reinterpret_cast<int4*>(&Ks[sr * 128 + (((sc + 4 * c) ^ (sr & 7)) * 8)]) = kreg[c];
#pragma unroll
    for (int jj = 0; jj < 8; ++jj) {
      u16x4 pk = {vreg[0][jj], vreg[1][jj], vreg[2][jj], vreg[3][jj]};
      *reinterpret_cast<u16x4*>(&Vt[(vd + jj) * 64 + (vk ^ (jj * 8))]) = pk;
    }
    __syncthreads();

    // prefetch next tile (latency hides under QK+softmax+PV)
    if (kt + 1 < KT) {
      const u16* kn = kg + (size_t)(kt + 1) * kvstep;
      const u16* vn = vg + (size_t)(kt + 1) * kvstep;
#pragma unroll
      for (int c = 0; c < 4; ++c) {
        kreg[c] = *reinterpret_cast<const int4*>(kn + c * 32);
        vreg[c] = *reinterpret_cast<const u16x8*>(vn + (size_t)c * (2 * D_OUT));
      }
    }

    const int kbase = kt * 64;
    if (kbase <= q0w + 31) {  // wave has unmasked keys in this tile
      // QK^T: S^T[key][q]; two 32-key groups
      f32x16 s0 = (f32x16)0.0f, s1 = (f32x16)0.0f;
#pragma unroll
      for (int ds = 0; ds < 8; ++ds) {
        const int off = (16 * ds + 8 * hi) ^ ((lo & 7) * 8);
        bf16x8 a0 = *reinterpret_cast<const bf16x8*>(&Ks[lo * 128 + off]);
        bf16x8 a1 = *reinterpret_cast<const bf16x8*>(&Ks[(32 + lo) * 128 + off]);
        s0 = __builtin_amdgcn_mfma_f32_32x32x16_bf16(a0, qf[ds], s0, 0, 0, 0);
        s1 = __builtin_amdgcn_mfma_f32_32x32x16_bf16(a1, qf[ds], s1, 0, 0, 0);
      }

      // causal mask (diag tiles only); scores already in log2 domain
      if (kbase + 63 > q0w) {
        const int qg = q0w + lo;
#pragma unroll
        for (int r = 0; r < 16; ++r) {
          const int koff = kbase + (r & 3) + 8 * (r >> 2) + 4 * hi;
          if (koff > qg) s0[r] = NEG_BIG;
          if (koff + 32 > qg) s1[r] = NEG_BIG;
        }
      }

      // in-lane row max over 32 + partner half
      float ma = s0[0];
#pragma unroll
      for (int r = 1; r < 16; ++r) ma = fmaxf(ma, s0[r]);
#pragma unroll
      for (int r = 0; r < 16; ++r) ma = fmaxf(ma, s1[r]);
      float mfull = fmaxf(ma, __shfl_xor(ma, 32));

      // T13 defer-rescale (log2 domain, thr 8)
      float rf = 1.0f;
      int skip = (mfull <= mrow + 8.0f);
      if (!skip) {
        rf = fexp2(mrow - mfull);
        mrow = mfull;
      }
      if (!__all(skip)) {
#pragma unroll
        for (int r = 0; r < 16; ++r) {
          float rb = __shfl(rf, ((r & 3) + 8 * (r >> 2)) + 4 * hi);
#pragma unroll
          for (int dt = 0; dt < 4; ++dt) ctx[dt][r] *= rb;
        }
      }

      // exp2 + in-lane sum
      float ps = 0.0f;
#pragma unroll
      for (int r = 0; r < 16; ++r) {
        s0[r] = fexp2(s0[r] - mrow);
        ps += s0[r];
      }
#pragma unroll
      for (int r = 0; r < 16; ++r) {
        s1[r] = fexp2(s1[r] - mrow);
        ps += s1[r];
      }
      ps += __shfl_xor(ps, 32);
      lrow = lrow * rf + ps;

      // P -> bf16 A-frags: one swap fills words j01 & j45
      bf16x8 pa[4];
#pragma unroll
      for (int g = 0; g < 2; ++g) {
        const f32x16& sg = g ? s1 : s0;
#pragma unroll
        for (int half = 0; half < 2; ++half) {
          const int rb = half * 8;
          unsigned w0 = cvtpk(sg[rb + 0], sg[rb + 1]);
          unsigned w2 = cvtpk(sg[rb + 4], sg[rb + 5]);
          unsigned w1 = cvtpk(sg[rb + 2], sg[rb + 3]);
          unsigned w3 = cvtpk(sg[rb + 6], sg[rb + 7]);
          swap32(w0, w2);
          swap32(w1, w3);
          u32x4 fr = {w0, w1, w2, w3};
          pa[2 * g + half] = __builtin_bit_cast(bf16x8, fr);
        }
      }

      // PV: ctx[dt] += P(32q x 16k) * V(16k x 32d)
#pragma unroll
      for (int dt = 0; dt < 4; ++dt) {
        const int vrow = 32 * dt + lo;
#pragma unroll
        for (int ks = 0; ks < 4; ++ks) {
          const int off = (16 * ks + 8 * hi) ^ ((lo & 7) * 8);
          bf16x8 bv = *reinterpret_cast<const bf16x8*>(&Vt[vrow * 64 + off]);
          ctx[dt] = __builtin_amdgcn_mfma_f32_32x32x16_bf16(pa[ks], bv, ctx[dt], 0, 0, 0);
        }
      }
    }
    __syncthreads();
  }

  // epilogue: per-q-row 1/l broadcast + store
  float linv = 1.0f / lrow;
#pragma unroll
  for (int r = 0; r < 16; ++r) {
    float lb = __shfl(linv, ((r & 3) + 8 * (r >> 2)) + 4 * hi);
    const int qr = q0w + (r & 3) + 8 * (r >> 2) + 4 * hi;
#pragma unroll
    for (int dt = 0; dt < 4; ++dt)
      Ob[(size_t)qr * D_OUT + dt * 32 + lo] = f2bf(ctx[dt][r] * lb);
  }
}

extern "C" void kernel_launch(void* const* d_in, const int* in_sizes, int n_in,
                              void* d_out, int out_size, void* d_ws, size_t ws_size,
                              hipStream_t stream) {
  const float* x    = (const float*)d_in[0];
  const float* Wq   = (const float*)d_in[1];
  const float* Wdkv = (const float*)d_in[2];
  const float* Wukv = (const float*)d_in[3];
  const float* Wout = (const float*)d_in[4];
  const float* bout = (const float*)d_in[5];
  float* out = (float*)d_out;

  char* ws = (char*)d_ws;
  size_t off = 0;
  auto alloc = [&](size_t bytes) -> void* {
    void* p = ws + off;
    off += (bytes + 255) & ~(size_t)255;
    return p;
  };
  u16* xb    = (u16*)alloc((size_t)Mtot * D_IN * 2);
  u16* wqT   = (u16*)alloc((size_t)D_OUT * D_IN * 2);
  u16* wdkvT = (u16*)alloc((size_t)LAT * D_IN * 2);
  u16* wukvT = (u16*)alloc((size_t)2 * D_OUT * LAT * 2);
  u16* woutT = (u16*)alloc((size_t)D_IN * D_OUT * 2);
  u16* q     = (u16*)alloc((size_t)Mtot * D_OUT * 2);
  u16* lat   = (u16*)alloc((size_t)Mtot * LAT * 2);
  u16* kv    = (u16*)alloc((size_t)Mtot * 2 * D_OUT * 2);
  u16* ctx   = (u16*)alloc((size_t)Mtot * D_OUT * 2);

  {
    int n = Mtot * D_IN;
    k_cvt<<<n / 4 / 256, 256, 0, stream>>>(x, xb, n);
  }
  k_tcvt<<<dim3(D_OUT / 32, D_IN / 32), dim3(32, 8), 0, stream>>>(Wq, wqT, D_IN, D_OUT);
  k_tcvt<<<dim3(LAT / 32, D_IN / 32), dim3(32, 8), 0, stream>>>(Wdkv, wdkvT, D_IN, LAT);
  k_tcvt<<<dim3(2 * D_OUT / 32, LAT / 32), dim3(32, 8), 0, stream>>>(Wukv, wukvT, LAT, 2 * D_OUT);
  k_tcvt<<<dim3(D_IN / 32, D_OUT / 32), dim3(32, 8), 0, stream>>>(Wout, woutT, D_OUT, D_IN);

  // q = (x @ Wq) * (1/sqrt(d) * log2e)
  k_gemm<2><<<(Mtot / 128) * (D_OUT / 128), 256, 0, stream>>>(xb, wqT, q, nullptr, QSCALE, Mtot, D_OUT, D_IN);
  // latent = x @ Wdkv
  k_gemm<0><<<(Mtot / 128) * (LAT / 128), 256, 0, stream>>>(xb, wdkvT, lat, nullptr, 1.0f, Mtot, LAT, D_IN);
  // kv = latent @ Wukv
  k_gemm<0><<<(Mtot / 128) * (2 * D_OUT / 128), 256, 0, stream>>>(lat, wukvT, kv, nullptr, 1.0f, Mtot, 2 * D_OUT, LAT);
  // attention
  k_attn<<<dim3(16 * 32), 256, 0, stream>>>(q, kv, ctx);
  // out = ctx @ Wout + b_out
  k_gemm<1><<<(Mtot / 128) * (D_IN / 128), 256, 0, stream>>>(ctx, woutT, out, bout, 1.0f, Mtot, D_IN, D_OUT);
}

// Round 4
// 276.759 us; speedup vs baseline: 1.6789x; 1.1196x over previous
//
#include <hip/hip_runtime.h>
#include <hip/hip_bf16.h>

typedef short bf16x8 __attribute__((ext_vector_type(8)));
typedef float f32x4 __attribute__((ext_vector_type(4)));
typedef float f32x16 __attribute__((ext_vector_type(16)));
typedef unsigned int u32x4 __attribute__((ext_vector_type(4)));
typedef unsigned short u16;
typedef unsigned short u16x4 __attribute__((ext_vector_type(4)));
typedef unsigned short u16x8 __attribute__((ext_vector_type(8)));

constexpr int D_IN = 2048, D_OUT = 2048, NH = 16, HD = 128, LAT = 256;
constexpr int Bb = 2, Ss = 2048, Mtot = Bb * Ss;  // 4096

// 1/sqrt(128) * log2(e): fold softmax scale + exp2 conversion into Q once
constexpr float QSCALE = 0.08838834764831845f * 1.4426950408889634f;
constexpr float NEG_BIG = -3.0e38f;

__device__ __forceinline__ u16 f2bf(float f) {
  unsigned u = __float_as_uint(f);
  unsigned r = ((u >> 16) & 1u) + 0x7fffu;  // RNE
  return (u16)((u + r) >> 16);
}

__device__ __forceinline__ float bf2f(u16 v) {
  return __uint_as_float((unsigned)v << 16);
}

__device__ __forceinline__ float fexp2(float x) {
#if __has_builtin(__builtin_amdgcn_exp2f)
  return __builtin_amdgcn_exp2f(x);
#else
  return exp2f(x);
#endif
}

__device__ __forceinline__ unsigned cvtpk(float lo, float hi) {
  unsigned r;
  asm("v_cvt_pk_bf16_f32 %0, %1, %2" : "=v"(r) : "v"(lo), "v"(hi));
  return r;
}

__device__ __forceinline__ void swap32(unsigned& a, unsigned& b) {
  asm volatile("v_permlane32_swap_b32 %0, %1" : "+v"(a), "+v"(b));
}

__device__ __forceinline__ void gload_lds16(const u16* g, u16* l) {
  __builtin_amdgcn_global_load_lds((const __attribute__((address_space(1))) void*)g,
                                   (__attribute__((address_space(3))) void*)l, 16, 0, 0);
}

// ---------- fp32 -> bf16 convert (vectorized) ----------
__global__ void k_cvt(const float* __restrict__ in, u16* __restrict__ out, int n) {
  int i = (blockIdx.x * blockDim.x + threadIdx.x) * 4;
  if (i >= n) return;
  float4 v = *reinterpret_cast<const float4*>(in + i);
  ushort4 o;
  o.x = f2bf(v.x); o.y = f2bf(v.y); o.z = f2bf(v.z); o.w = f2bf(v.w);
  *reinterpret_cast<ushort4*>(out + i) = o;
}

// ---------- transpose + convert: in [K][N] f32 -> out [N][K] bf16 ----------
__global__ void k_tcvt(const float* __restrict__ in, u16* __restrict__ out, int K, int N) {
  __shared__ float t[32][33];
  int bx = blockIdx.x * 32;  // N
  int by = blockIdx.y * 32;  // K
  int tx = threadIdx.x, ty = threadIdx.y;
#pragma unroll
  for (int j = 0; j < 32; j += 8)
    t[ty + j][tx] = in[(size_t)(by + ty + j) * N + bx + tx];
  __syncthreads();
#pragma unroll
  for (int j = 0; j < 32; j += 8)
    out[(size_t)(bx + ty + j) * K + by + tx] = f2bf(t[tx][ty + j]);
}

// ---------- GEMM: C[M,N] = A[M,K](bf16 rm) x Bt[N,K](bf16 rm)^T ----------
template <int OUT_MODE>  // 0: bf16, 1: f32 + bias, 2: bf16 * scale
__global__ __launch_bounds__(256) void k_gemm(const u16* __restrict__ A,
                                              const u16* __restrict__ Bt,
                                              void* __restrict__ Cp,
                                              const float* __restrict__ bias,
                                              float scale, int M, int N, int K) {
  constexpr int BK = 32;
  __shared__ u16 As[128 * BK];
  __shared__ u16 Bs[128 * BK];
  const int nbx = N >> 7;
  const int bx = blockIdx.x % nbx, by = blockIdx.x / nbx;
  const int row0 = by << 7, col0 = bx << 7;
  const int tid = threadIdx.x;
  const int wave = tid >> 6, lane = tid & 63;
  const int wr = (wave >> 1) * 64, wc = (wave & 1) * 64;
  const int lr = lane & 15, lg = lane >> 4;

  f32x4 acc[4][4];
#pragma unroll
  for (int m = 0; m < 4; ++m)
#pragma unroll
    for (int n = 0; n < 4; ++n) acc[m][n] = (f32x4)0.0f;

  const int crow = lane >> 2, ccol = (lane & 3) * 8;
  const u16* gA0 = A + (size_t)(row0 + wave * 32 + crow) * K + ccol;
  const u16* gA1 = gA0 + (size_t)16 * K;
  const u16* gB0 = Bt + (size_t)(col0 + wave * 32 + crow) * K + ccol;
  const u16* gB1 = gB0 + (size_t)16 * K;
  u16* lA0 = &As[(wave * 32) * BK];
  u16* lA1 = &As[(wave * 32 + 16) * BK];
  u16* lB0 = &Bs[(wave * 32) * BK];
  u16* lB1 = &Bs[(wave * 32 + 16) * BK];

  for (int k0 = 0; k0 < K; k0 += BK) {
    gload_lds16(gA0 + k0, lA0);
    gload_lds16(gA1 + k0, lA1);
    gload_lds16(gB0 + k0, lB0);
    gload_lds16(gB1 + k0, lB1);
    __syncthreads();
    bf16x8 af[4], bfr[4];
#pragma unroll
    for (int m = 0; m < 4; ++m)
      af[m] = *reinterpret_cast<const bf16x8*>(&As[(wr + m * 16 + lr) * BK + lg * 8]);
#pragma unroll
    for (int n = 0; n < 4; ++n)
      bfr[n] = *reinterpret_cast<const bf16x8*>(&Bs[(wc + n * 16 + lr) * BK + lg * 8]);
    __builtin_amdgcn_s_setprio(1);
#pragma unroll
    for (int m = 0; m < 4; ++m)
#pragma unroll
      for (int n = 0; n < 4; ++n)
        acc[m][n] = __builtin_amdgcn_mfma_f32_16x16x32_bf16(af[m], bfr[n], acc[m][n], 0, 0, 0);
    __builtin_amdgcn_s_setprio(0);
    __syncthreads();
  }

#pragma unroll
  for (int m = 0; m < 4; ++m) {
    const int r = row0 + wr + m * 16 + lg * 4;
#pragma unroll
    for (int n = 0; n < 4; ++n) {
      const int c = col0 + wc + n * 16 + lr;
#pragma unroll
      for (int i = 0; i < 4; ++i) {
        float v = acc[m][n][i];
        if (OUT_MODE == 0)
          ((u16*)Cp)[(size_t)(r + i) * N + c] = f2bf(v);
        else if (OUT_MODE == 1)
          ((float*)Cp)[(size_t)(r + i) * N + c] = v + bias[c];
        else
          ((u16*)Cp)[(size_t)(r + i) * N + c] = f2bf(v * scale);
      }
    }
  }
}

// ---------- small-N GEMM: 64x64 tile (for N=256 latent projection) ----------
__global__ __launch_bounds__(256) void k_gemm64(const u16* __restrict__ A,
                                                const u16* __restrict__ Bt,
                                                u16* __restrict__ C,
                                                int M, int N, int K) {
  constexpr int BK = 32;
  __shared__ u16 As[64 * BK];
  __shared__ u16 Bs[64 * BK];
  const int nbx = N >> 6;
  const int bx = blockIdx.x % nbx, by = blockIdx.x / nbx;
  const int row0 = by << 6, col0 = bx << 6;
  const int tid = threadIdx.x;
  const int wave = tid >> 6, lane = tid & 63;
  const int wr = (wave >> 1) * 32, wc = (wave & 1) * 32;
  const int lr = lane & 15, lg = lane >> 4;

  f32x4 acc[2][2];
#pragma unroll
  for (int m = 0; m < 2; ++m)
#pragma unroll
    for (int n = 0; n < 2; ++n) acc[m][n] = (f32x4)0.0f;

  const int crow = lane >> 2, ccol = (lane & 3) * 8;
  const u16* gA = A + (size_t)(row0 + wave * 16 + crow) * K + ccol;
  const u16* gB = Bt + (size_t)(col0 + wave * 16 + crow) * K + ccol;
  u16* lA = &As[(wave * 16) * BK];
  u16* lB = &Bs[(wave * 16) * BK];

  for (int k0 = 0; k0 < K; k0 += BK) {
    gload_lds16(gA + k0, lA);
    gload_lds16(gB + k0, lB);
    __syncthreads();
    bf16x8 af[2], bfr[2];
#pragma unroll
    for (int m = 0; m < 2; ++m)
      af[m] = *reinterpret_cast<const bf16x8*>(&As[(wr + m * 16 + lr) * BK + lg * 8]);
#pragma unroll
    for (int n = 0; n < 2; ++n)
      bfr[n] = *reinterpret_cast<const bf16x8*>(&Bs[(wc + n * 16 + lr) * BK + lg * 8]);
#pragma unroll
    for (int m = 0; m < 2; ++m)
#pragma unroll
      for (int n = 0; n < 2; ++n)
        acc[m][n] = __builtin_amdgcn_mfma_f32_16x16x32_bf16(af[m], bfr[n], acc[m][n], 0, 0, 0);
    __syncthreads();
  }

#pragma unroll
  for (int m = 0; m < 2; ++m) {
    const int r = row0 + wr + m * 16 + lg * 4;
#pragma unroll
    for (int n = 0; n < 2; ++n) {
      const int c = col0 + wc + n * 16 + lr;
#pragma unroll
      for (int i = 0; i < 4; ++i)
        C[(size_t)(r + i) * N + c] = f2bf(acc[m][n][i]);
    }
  }
}

// ---------- causal flash attention, piece-decomposed for load balance ----------
// 24 pieces per (b,h): strips qb>=8 split into two KV-halves (flash-decode,
// combined by k_comb); strips qb<=7 whole. Pieces sorted big-first (LPT).
__device__ __constant__ const signed char PT_qb[24] = {15,15,7,14,14,13,13,6,12,12,11,11,5,10,10,9,9,4,8,8,3,2,1,0};
__device__ __constant__ const signed char PT_md[24] = {1,2,0,1,2,1,2,0,1,2,1,2,0,1,2,1,2,0,1,2,0,0,0,0};
__device__ __constant__ const signed char PT_k0[24] = {0,16,0,0,15,0,14,0,0,13,0,12,0,0,11,0,10,0,0,9,0,0,0,0};
__device__ __constant__ const signed char PT_k1[24] = {16,32,16,15,30,14,28,14,13,26,12,24,12,11,22,10,20,10,9,18,8,6,4,2};

__global__ __launch_bounds__(256) void k_attn(const u16* __restrict__ Q,
                                              const u16* __restrict__ KV,
                                              u16* __restrict__ O,
                                              u16* __restrict__ o_part,
                                              float* __restrict__ mlbuf) {
  __shared__ __align__(16) u16 Ks[64 * 128];  // [key][d], chunk ^= (key&7)
  __shared__ __align__(16) u16 Vt[128 * 64];  // [d][key], key ^= (d&7)*8
  const int p = blockIdx.x >> 5, bh = blockIdx.x & 31;
  const int qb = PT_qb[p], mode = PT_md[p];
  const int kt0 = PT_k0[p], kt1 = PT_k1[p];
  const int b = bh >> 4, h = bh & 15;
  const u16* Qb = Q + (size_t)b * Ss * D_OUT + h * HD;
  const u16* Kb = KV + (size_t)b * Ss * (2 * D_OUT) + h * HD;
  const u16* Vb = Kb + D_OUT;
  u16* Ob = O + (size_t)b * Ss * D_OUT + h * HD;

  const int tid = threadIdx.x, wave = tid >> 6, lane = tid & 63;
  const int lo = lane & 31, hi = lane >> 5;
  const int q0w = qb * 128 + wave * 32;  // wave's first q-row

  // Q fragments (B-operand): col=q=lane&31, k=d
  bf16x8 qf[8];
  {
    const u16* qsrc = Qb + (size_t)(q0w + lo) * D_OUT + hi * 8;
#pragma unroll
    for (int ds = 0; ds < 8; ++ds)
      qf[ds] = *reinterpret_cast<const bf16x8*>(qsrc + ds * 16);
  }

  f32x16 ctx[4];
#pragma unroll
  for (int dt = 0; dt < 4; ++dt) ctx[dt] = (f32x16)0.0f;
  float mrow = NEG_BIG, lrow = 0.0f;

  // staging roles
  const int sr = tid >> 2, sc = tid & 3;
  const int vk = (tid & 15) * 4, vd = (tid >> 4) * 8;
  const size_t kvstep = (size_t)64 * 2 * D_OUT;
  const u16* kg = Kb + (size_t)kt0 * kvstep + (size_t)sr * (2 * D_OUT) + sc * 8;
  const u16* vg = Vb + (size_t)kt0 * kvstep + (size_t)vk * (2 * D_OUT) + vd;

  int4 kreg[4];
  u16x8 vreg[4];
#pragma unroll
  for (int c = 0; c < 4; ++c) {
    kreg[c] = *reinterpret_cast<const int4*>(kg + c * 32);
    vreg[c] = *reinterpret_cast<const u16x8*>(vg + (size_t)c * (2 * D_OUT));
  }

  for (int kt = kt0; kt < kt1; ++kt) {
    // staged regs -> swizzled LDS
#pragma unroll
    for (int c = 0; c < 4; ++c)
      *reinterpret_cast<int4*>(&Ks[sr * 128 + (((sc + 4 * c) ^ (sr & 7)) * 8)]) = kreg[c];
#pragma unroll
    for (int jj = 0; jj < 8; ++jj) {
      u16x4 pk = {vreg[0][jj], vreg[1][jj], vreg[2][jj], vreg[3][jj]};
      *reinterpret_cast<u16x4*>(&Vt[(vd + jj) * 64 + (vk ^ (jj * 8))]) = pk;
    }
    __syncthreads();

    // prefetch next tile (latency hides under QK+softmax+PV)
    if (kt + 1 < kt1) {
      const u16* kn = kg + (size_t)(kt + 1 - kt0) * kvstep;
      const u16* vn = vg + (size_t)(kt + 1 - kt0) * kvstep;
#pragma unroll
      for (int c = 0; c < 4; ++c) {
        kreg[c] = *reinterpret_cast<const int4*>(kn + c * 32);
        vreg[c] = *reinterpret_cast<const u16x8*>(vn + (size_t)c * (2 * D_OUT));
      }
    }

    const int kbase = kt * 64;
    if (kbase <= q0w + 31) {  // wave has unmasked keys in this tile
      // QK^T: S^T[key][q]; two 32-key groups
      f32x16 s0 = (f32x16)0.0f, s1 = (f32x16)0.0f;
      __builtin_amdgcn_s_setprio(1);
#pragma unroll
      for (int ds = 0; ds < 8; ++ds) {
        const int off = (16 * ds + 8 * hi) ^ ((lo & 7) * 8);
        bf16x8 a0 = *reinterpret_cast<const bf16x8*>(&Ks[lo * 128 + off]);
        bf16x8 a1 = *reinterpret_cast<const bf16x8*>(&Ks[(32 + lo) * 128 + off]);
        s0 = __builtin_amdgcn_mfma_f32_32x32x16_bf16(a0, qf[ds], s0, 0, 0, 0);
        s1 = __builtin_amdgcn_mfma_f32_32x32x16_bf16(a1, qf[ds], s1, 0, 0, 0);
      }
      __builtin_amdgcn_s_setprio(0);

      // causal mask (diag tiles only); scores already in log2 domain
      if (kbase + 63 > q0w) {
        const int qg = q0w + lo;
#pragma unroll
        for (int r = 0; r < 16; ++r) {
          const int koff = kbase + (r & 3) + 8 * (r >> 2) + 4 * hi;
          if (koff > qg) s0[r] = NEG_BIG;
          if (koff + 32 > qg) s1[r] = NEG_BIG;
        }
      }

      // in-lane row max + partner half
      float ma = s0[0];
#pragma unroll
      for (int r = 1; r < 16; ++r) ma = fmaxf(ma, s0[r]);
#pragma unroll
      for (int r = 0; r < 16; ++r) ma = fmaxf(ma, s1[r]);
      float mfull = fmaxf(ma, __shfl_xor(ma, 32));

      // T13 defer-rescale (log2 domain, thr 8)
      float rf = 1.0f;
      int skip = (mfull <= mrow + 8.0f);
      if (!skip) {
        rf = fexp2(mrow - mfull);
        mrow = mfull;
      }
      if (!__all(skip)) {
#pragma unroll
        for (int r = 0; r < 16; ++r) {
          float rb = __shfl(rf, ((r & 3) + 8 * (r >> 2)) + 4 * hi);
#pragma unroll
          for (int dt = 0; dt < 4; ++dt) ctx[dt][r] *= rb;
        }
      }

      // exp2 + in-lane sum
      float ps = 0.0f;
#pragma unroll
      for (int r = 0; r < 16; ++r) {
        s0[r] = fexp2(s0[r] - mrow);
        ps += s0[r];
      }
#pragma unroll
      for (int r = 0; r < 16; ++r) {
        s1[r] = fexp2(s1[r] - mrow);
        ps += s1[r];
      }
      ps += __shfl_xor(ps, 32);
      lrow = lrow * rf + ps;

      // P -> bf16 A-frags: one swap fills words j01 & j45
      bf16x8 pa[4];
#pragma unroll
      for (int g = 0; g < 2; ++g) {
        const f32x16& sg = g ? s1 : s0;
#pragma unroll
        for (int half = 0; half < 2; ++half) {
          const int rb = half * 8;
          unsigned w0 = cvtpk(sg[rb + 0], sg[rb + 1]);
          unsigned w2 = cvtpk(sg[rb + 4], sg[rb + 5]);
          unsigned w1 = cvtpk(sg[rb + 2], sg[rb + 3]);
          unsigned w3 = cvtpk(sg[rb + 6], sg[rb + 7]);
          swap32(w0, w2);
          swap32(w1, w3);
          u32x4 fr = {w0, w1, w2, w3};
          pa[2 * g + half] = __builtin_bit_cast(bf16x8, fr);
        }
      }

      // PV: ctx[dt] += P(32q x 16k) * V(16k x 32d)
      __builtin_amdgcn_s_setprio(1);
#pragma unroll
      for (int dt = 0; dt < 4; ++dt) {
        const int vrow = 32 * dt + lo;
#pragma unroll
        for (int ks = 0; ks < 4; ++ks) {
          const int off = (16 * ks + 8 * hi) ^ ((lo & 7) * 8);
          bf16x8 bv = *reinterpret_cast<const bf16x8*>(&Vt[vrow * 64 + off]);
          ctx[dt] = __builtin_amdgcn_mfma_f32_32x32x16_bf16(pa[ks], bv, ctx[dt], 0, 0, 0);
        }
      }
      __builtin_amdgcn_s_setprio(0);
    }
    __syncthreads();
  }

  if (mode == 0) {
    // whole strip: normalize + store bf16 ctx
    float linv = 1.0f / lrow;
#pragma unroll
    for (int r = 0; r < 16; ++r) {
      float lb = __shfl(linv, ((r & 3) + 8 * (r >> 2)) + 4 * hi);
      const int qr = q0w + (r & 3) + 8 * (r >> 2) + 4 * hi;
#pragma unroll
      for (int dt = 0; dt < 4; ++dt)
        Ob[(size_t)qr * D_OUT + dt * 32 + lo] = f2bf(ctx[dt][r] * lb);
    }
  } else {
    // split piece: store unnormalized partial + per-row (m, l)
    const int part = mode - 1;
    const int slot = bh * 8 + (qb - 8);
    u16* po = o_part + ((size_t)slot * 2 + part) * (128 * 128);
    float* pm = mlbuf + ((size_t)slot * 2 + part) * (128 * 2);
#pragma unroll
    for (int r = 0; r < 16; ++r) {
      const int rl = wave * 32 + (r & 3) + 8 * (r >> 2) + 4 * hi;
#pragma unroll
      for (int dt = 0; dt < 4; ++dt)
        po[rl * 128 + dt * 32 + lo] = f2bf(ctx[dt][r]);
    }
    if (hi == 0) {
      const int rl = wave * 32 + lo;
      pm[rl * 2] = mrow;
      pm[rl * 2 + 1] = lrow;
    }
  }
}

// ---------- combine split-strip partials ----------
__global__ __launch_bounds__(256) void k_comb(const u16* __restrict__ o_part,
                                              const float* __restrict__ mlbuf,
                                              u16* __restrict__ O) {
  const int s = blockIdx.x;  // 0..255
  const int bh = s >> 3, qb = 8 + (s & 7);
  const int b = bh >> 4, h = bh & 15;
  u16* Ob = O + (size_t)b * Ss * D_OUT + h * HD;
  const u16* po = o_part + (size_t)s * 2 * 128 * 128;
  const float* pm = mlbuf + (size_t)s * 2 * 128 * 2;
  const int tid = threadIdx.x;
  const int r0 = tid >> 4, dg = (tid & 15) * 8;
#pragma unroll
  for (int rp = 0; rp < 8; ++rp) {
    const int row = rp * 16 + r0;
    float m1 = pm[row * 2], l1 = pm[row * 2 + 1];
    float m2 = pm[256 + row * 2], l2 = pm[256 + row * 2 + 1];
    float mm = fmaxf(m1, m2);
    float w1 = fexp2(m1 - mm), w2 = fexp2(m2 - mm);
    float inv = 1.0f / (l1 * w1 + l2 * w2);
    u16x8 o1 = *reinterpret_cast<const u16x8*>(po + row * 128 + dg);
    u16x8 o2 = *reinterpret_cast<const u16x8*>(po + 16384 + row * 128 + dg);
    u16x8 o;
#pragma unroll
    for (int j = 0; j < 8; ++j)
      o[j] = f2bf((bf2f(o1[j]) * w1 + bf2f(o2[j]) * w2) * inv);
    *reinterpret_cast<u16x8*>(&Ob[(size_t)(qb * 128 + row) * D_OUT + dg]) = o;
  }
}

extern "C" void kernel_launch(void* const* d_in, const int* in_sizes, int n_in,
                              void* d_out, int out_size, void* d_ws, size_t ws_size,
                              hipStream_t stream) {
  const float* x    = (const float*)d_in[0];
  const float* Wq   = (const float*)d_in[1];
  const float* Wdkv = (const float*)d_in[2];
  const float* Wukv = (const float*)d_in[3];
  const float* Wout = (const float*)d_in[4];
  const float* bout = (const float*)d_in[5];
  float* out = (float*)d_out;

  char* ws = (char*)d_ws;
  size_t off = 0;
  auto alloc = [&](size_t bytes) -> void* {
    void* p = ws + off;
    off += (bytes + 255) & ~(size_t)255;
    return p;
  };
  u16* xb    = (u16*)alloc((size_t)Mtot * D_IN * 2);
  u16* wqT   = (u16*)alloc((size_t)D_OUT * D_IN * 2);
  u16* wdkvT = (u16*)alloc((size_t)LAT * D_IN * 2);
  u16* wukvT = (u16*)alloc((size_t)2 * D_OUT * LAT * 2);
  u16* woutT = (u16*)alloc((size_t)D_IN * D_OUT * 2);
  u16* q     = (u16*)alloc((size_t)Mtot * D_OUT * 2);
  u16* lat   = (u16*)alloc((size_t)Mtot * LAT * 2);
  u16* kv    = (u16*)alloc((size_t)Mtot * 2 * D_OUT * 2);
  u16* ctx   = (u16*)alloc((size_t)Mtot * D_OUT * 2);
  u16* opart = (u16*)alloc((size_t)256 * 2 * 128 * 128 * 2);  // 16.8 MB
  float* mlp = (float*)alloc((size_t)256 * 2 * 128 * 2 * 4);  // 0.5 MB

  {
    int n = Mtot * D_IN;
    k_cvt<<<n / 4 / 256, 256, 0, stream>>>(x, xb, n);
  }
  k_tcvt<<<dim3(D_OUT / 32, D_IN / 32), dim3(32, 8), 0, stream>>>(Wq, wqT, D_IN, D_OUT);
  k_tcvt<<<dim3(LAT / 32, D_IN / 32), dim3(32, 8), 0, stream>>>(Wdkv, wdkvT, D_IN, LAT);
  k_tcvt<<<dim3(2 * D_OUT / 32, LAT / 32), dim3(32, 8), 0, stream>>>(Wukv, wukvT, LAT, 2 * D_OUT);
  k_tcvt<<<dim3(D_IN / 32, D_OUT / 32), dim3(32, 8), 0, stream>>>(Wout, woutT, D_OUT, D_IN);

  // q = (x @ Wq) * (1/sqrt(d) * log2e)
  k_gemm<2><<<(Mtot / 128) * (D_OUT / 128), 256, 0, stream>>>(xb, wqT, q, nullptr, QSCALE, Mtot, D_OUT, D_IN);
  // latent = x @ Wdkv  (N=256 -> 64x64 tiles, 256 blocks)
  k_gemm64<<<(Mtot / 64) * (LAT / 64), 256, 0, stream>>>(xb, wdkvT, lat, Mtot, LAT, D_IN);
  // kv = latent @ Wukv
  k_gemm<0><<<(Mtot / 128) * (2 * D_OUT / 128), 256, 0, stream>>>(lat, wukvT, kv, nullptr, 1.0f, Mtot, 2 * D_OUT, LAT);
  // attention (piece-decomposed) + combine
  k_attn<<<dim3(24 * 32), 256, 0, stream>>>(q, kv, ctx, opart, mlp);
  k_comb<<<dim3(256), 256, 0, stream>>>(opart, mlp, ctx);
  // out = ctx @ Wout + b_out
  k_gemm<1><<<(Mtot / 128) * (D_IN / 128), 256, 0, stream>>>(ctx, woutT, out, bout, 1.0f, Mtot, D_IN, D_OUT);
}